// Round 4
// baseline (112.729 us; speedup 1.0000x reference)
//
#include <hip/hip_runtime.h>

#define B 16
#define S 4096
#define V 128
#define TRUNC 11
#define T_LIM (S - TRUNC)   // 4085

#define NC 128              // chunks over t (compile-time)
#define CT (S / NC)         // 32
#define BV (B * V)          // 2048

// log2(0.99), 1/0.99
#define LOG2_GAMMA (-0.014499569695115089f)
#define INV_GAMMA 1.0101010101010102f

__device__ __forceinline__ float log_sigmoid(float x) {
    float e = __expf(-fabsf(x));
    return fminf(x, 0.0f) - __logf(1.0f + e);
}

// Thread (c, b, v4) computes per-v chunk partials:
//   A = sum_{t in chunk} w[t]*ls[t]*local_acc[t]
//   W = sum_{t in chunk} w[t]*ls[t]
//   L = sum_{t in chunk, t<T} lp[t]
// Stores in NATURAL [c][b][v] layout: p*[tid] — one coalesced full-line
// float4 store per array (no cross-XCD partial-line write amplification).
__global__ __launch_bounds__(256) void partials_kernel(
    const float4* __restrict__ lp,   // [S][B][V/4]
    const float4* __restrict__ lg,   // [B][S][V/4]
    float4* __restrict__ pA,         // [NC][B][V/4]
    float4* __restrict__ pW,
    float4* __restrict__ pL)
{
    int tid = blockIdx.x * blockDim.x + threadIdx.x;   // 65536 threads
    int v4 = tid & (V / 4 - 1);          // 0..31
    int b  = (tid >> 5) & (B - 1);       // 0..15
    int c  = tid >> 9;                   // 0..NC-1
    int t0 = c * CT;

    const float4* lp_p = lp + (size_t)t0 * (B * V / 4) + b * (V / 4) + v4;
    const float4* lg_p = lg + (size_t)b * (S * V / 4) + (size_t)t0 * (V / 4) + v4;

    float w = exp2f(LOG2_GAMMA * (float)(S - t0));

    float ax = 0.f, ay = 0.f, az = 0.f, aw = 0.f;
    float Ax = 0.f, Ay = 0.f, Az = 0.f, Aw = 0.f;
    float Wx = 0.f, Wy = 0.f, Wz = 0.f, Ww = 0.f;

    #pragma unroll 8
    for (int i = 0; i < CT; ++i) {
        int t = t0 + i;
        float4 l = lp_p[(size_t)i * (B * V / 4)];
        float4 x = lg_p[(size_t)i * (V / 4)];
        if (t < T_LIM) {                 // wave-uniform
            ax += l.x; ay += l.y; az += l.z; aw += l.w;
        }
        float sx = w * log_sigmoid(x.x);
        float sy = w * log_sigmoid(x.y);
        float sz = w * log_sigmoid(x.z);
        float sw = w * log_sigmoid(x.w);
        Ax = fmaf(sx, ax, Ax);
        Ay = fmaf(sy, ay, Ay);
        Az = fmaf(sz, az, Az);
        Aw = fmaf(sw, aw, Aw);
        Wx += sx; Wy += sy; Wz += sz; Ww += sw;
        w *= INV_GAMMA;
    }

    pA[tid] = make_float4(Ax, Ay, Az, Aw);
    pW[tid] = make_float4(Wx, Wy, Wz, Ww);
    pL[tid] = make_float4(ax, ay, az, aw);
}

// One wave per (b,v). Lane l owns chunks 2l and 2l+1 (scattered scalar
// loads from the 3 MB cache-resident partials — cheap on the read side).
// Exclusive scan of L across chunks -> prefix; E = sum(A + prefix*W).
__global__ __launch_bounds__(256) void combine_kernel(
    const float* __restrict__ pA,    // [NC][BV]
    const float* __restrict__ pW,
    const float* __restrict__ pL,
    float* __restrict__ out)
{
    int gtid = blockIdx.x * blockDim.x + threadIdx.x;
    int bv   = gtid >> 6;
    int lane = threadIdx.x & 63;
    if (bv >= BV) return;

    size_t i0 = (size_t)(lane * 2) * BV + bv;
    float A0 = pA[i0], A1 = pA[i0 + BV];
    float W0 = pW[i0], W1 = pW[i0 + BV];
    float L0 = pL[i0], L1 = pL[i0 + BV];

    float s = L0 + L1;                   // lane total of L

    // inclusive wave scan of s, then make exclusive
    float scan = s;
    #pragma unroll
    for (int off = 1; off < 64; off <<= 1) {
        float n = __shfl_up(scan, off, 64);
        if (lane >= off) scan += n;
    }
    float base = scan - s;               // prefix before chunk 2*lane

    float E = A0 + A1;
    E = fmaf(base,      W0, E);
    E = fmaf(base + L0, W1, E);

    #pragma unroll
    for (int off = 32; off > 0; off >>= 1)
        E += __shfl_down(E, off, 64);

    if (lane == 0) out[bv] = E;
}

// Fallback (ws too small): one thread per (b, v4), full-S scan, direct out.
__global__ __launch_bounds__(256) void direct_kernel(
    const float4* __restrict__ lp,
    const float4* __restrict__ lg,
    float4* __restrict__ out)
{
    int tid = blockIdx.x * blockDim.x + threadIdx.x;
    if (tid >= B * V / 4) return;
    int v4 = tid & (V / 4 - 1);
    int b  = tid >> 5;

    const float4* lp_p = lp + b * (V / 4) + v4;
    const float4* lg_p = lg + (size_t)b * (S * V / 4) + v4;

    float w = exp2f(LOG2_GAMMA * (float)S);
    float ax = 0.f, ay = 0.f, az = 0.f, aw = 0.f;
    float Ax = 0.f, Ay = 0.f, Az = 0.f, Aw = 0.f;
    for (int t = 0; t < S; ++t) {
        float4 l = lp_p[(size_t)t * (B * V / 4)];
        float4 x = lg_p[(size_t)t * (V / 4)];
        if (t < T_LIM) { ax += l.x; ay += l.y; az += l.z; aw += l.w; }
        Ax = fmaf(w * log_sigmoid(x.x), ax, Ax);
        Ay = fmaf(w * log_sigmoid(x.y), ay, Ay);
        Az = fmaf(w * log_sigmoid(x.z), az, Az);
        Aw = fmaf(w * log_sigmoid(x.w), aw, Aw);
        w *= INV_GAMMA;
    }
    out[tid] = make_float4(Ax, Ay, Az, Aw);
}

extern "C" void kernel_launch(void* const* d_in, const int* in_sizes, int n_in,
                              void* d_out, int out_size, void* d_ws, size_t ws_size,
                              hipStream_t stream)
{
    const float4* lp = (const float4*)d_in[0];   // log_probs [S,B,V] f32
    const float4* lg = (const float4*)d_in[1];   // logits    [B,S,V] f32
    float* out = (float*)d_out;                   // [B,V] f32

    size_t per = (size_t)NC * BV;                 // floats per partial array

    if (per * 3 * sizeof(float) > ws_size) {
        direct_kernel<<<(B * V / 4 + 255) / 256, 256, 0, stream>>>(
            lp, lg, (float4*)d_out);
        return;
    }

    float* pA = (float*)d_ws;
    float* pW = pA + per;
    float* pL = pW + per;

    int threads1 = NC * (B * V / 4);              // 65536
    partials_kernel<<<threads1 / 256, 256, 0, stream>>>(
        lp, lg, (float4*)pA, (float4*)pW, (float4*)pL);

    int threads2 = BV * 64;                       // 131072
    combine_kernel<<<threads2 / 256, 256, 0, stream>>>(pA, pW, pL, out);
}